// Round 10
// baseline (269.233 us; speedup 1.0000x reference)
//
#include <hip/hip_runtime.h>

#define HID 128
#define NNODE 10000
#define KN 16
#define ROWS 80000    // BATCH * NNODE
#define NTILES 2500   // ROWS / 32
#define ANCH 313      // ceil(NNODE/32) aggr row-chunks
#define AGRID (8 * 2 * ANCH)   // 5008 aggr blocks

typedef __attribute__((ext_vector_type(8))) short short8;   // 8 bf16 (4 VGPRs)
typedef __attribute__((ext_vector_type(4))) float f32x4;
typedef __attribute__((ext_vector_type(2))) float f32x2;
typedef __attribute__((ext_vector_type(2))) unsigned int u32x2;

__device__ __forceinline__ unsigned short f2b(float f) {
    unsigned u = __float_as_uint(f);
    u += 0x7FFFu + ((u >> 16) & 1u);       // round-to-nearest-even
    return (unsigned short)(u >> 16);
}

// Weight transpose+convert: W1t[128][64], W2t[128][128], Wu1t[128][256],
// Wu2t384[128][384] (dup rows: k<128->Wu2[k], 128..255->Wu2[k-128], 256..383->Wu2[k-128]),
// Wu2t256[128][256] (fallback). 139264 elems.
__global__ __launch_bounds__(256) void wconv_all(
    const float* __restrict__ W1, const float* __restrict__ W2,
    const float* __restrict__ Wu1, const float* __restrict__ Wu2,
    unsigned short* __restrict__ W1t, unsigned short* __restrict__ W2t,
    unsigned short* __restrict__ Wu1t, unsigned short* __restrict__ Wu2t384,
    unsigned short* __restrict__ Wu2t256) {
    int idx = blockIdx.x * 256 + threadIdx.x;   // < 139264
    if (idx < 8192) {
        int n = idx & 127, k = idx >> 7;
        W1t[n * 64 + k] = f2b(W1[k * 128 + n]);
    } else if (idx < 24576) {
        int off = idx - 8192; int n = off & 127, k = off >> 7;
        W2t[n * 128 + k] = f2b(W2[k * 128 + n]);
    } else if (idx < 57344) {
        int off = idx - 24576; int n = off & 127, k = off >> 7;
        Wu1t[n * 256 + k] = f2b(Wu1[k * 128 + n]);
    } else if (idx < 106496) {
        int off = idx - 57344; int n = off % 128, k = off / 128;   // k<384
        int sr = k < 256 ? (k & 127) : (k - 128);
        Wu2t384[n * 384 + k] = f2b(Wu2[sr * 128 + n]);
    } else {
        int off = idx - 106496; int n = off & 127, k = off >> 7;
        Wu2t256[n * 256 + k] = f2b(Wu2[k * 128 + n]);
    }
}

// ---- embed role: Y[r][:] = relu(X[r][:]@W + b); transposed-operand MFMA,
// persistent W-frags, stride loop, 2-deep x pipeline. Tiles >= NTILES -> (A1,Y1).
template<int K, bool AF32>
__device__ __forceinline__ void embed_role(
    int lb, int stride, int tot,
    const void* __restrict__ A0, const void* __restrict__ A1,
    const unsigned short* __restrict__ Wt, const float* __restrict__ bias,
    unsigned short* __restrict__ Y0, unsigned short* __restrict__ Y1) {
    const int t = threadIdx.x, w = t >> 6, lane = t & 63;
    const int lrow = lane & 15, lk = lane >> 4;
    const int rs = w & 1, ng = w >> 1;
    const int col0 = ng * 32;

    short8 wf[2][K / 32];
    f32x4 bv[2];
#pragma unroll
    for (int p = 0; p < 2; ++p) {
        bv[p] = *(const f32x4*)(bias + col0 + p * 16 + lk * 4);
#pragma unroll
        for (int kt = 0; kt < K / 32; ++kt)
            wf[p][kt] = *(const short8*)(Wt + (col0 + p * 16 + lrow) * K + kt * 32 + lk * 8);
    }

    int T = lb;
    if (T >= tot) return;

    auto loadx = [&](int TT, short8* xf) {
        const int half = TT >= NTILES;
        const void* A = half ? A1 : A0;
        const int row = (TT - half * NTILES) * 32 + rs * 16 + lrow;
        if constexpr (AF32) {
            const float* X = (const float*)A + (size_t)row * K;
#pragma unroll
            for (int kt = 0; kt < K / 32; ++kt) {
                f32x4 f0 = *(const f32x4*)(X + kt * 32 + lk * 8);
                f32x4 f1 = *(const f32x4*)(X + kt * 32 + lk * 8 + 4);
                short8 v;
#pragma unroll
                for (int e = 0; e < 4; ++e) { v[e] = (short)f2b(f0[e]); v[4 + e] = (short)f2b(f1[e]); }
                xf[kt] = v;
            }
        } else {
            const unsigned short* X = (const unsigned short*)A + (size_t)row * K;
#pragma unroll
            for (int kt = 0; kt < K / 32; ++kt)
                xf[kt] = *(const short8*)(X + kt * 32 + lk * 8);
        }
    };

    short8 xf[K / 32], xn[K / 32];
    loadx(T, xf);
    for (;;) {
        const int Tn = T + stride;
        const bool more = Tn < tot;
        if (more) loadx(Tn, xn);

        const int half = T >= NTILES;
        unsigned short* Y = half ? Y1 : Y0;
        const int row = (T - half * NTILES) * 32 + rs * 16 + lrow;
#pragma unroll
        for (int p = 0; p < 2; ++p) {
            f32x4 acc = {0.f, 0.f, 0.f, 0.f};
#pragma unroll
            for (int kt = 0; kt < K / 32; ++kt)
                acc = __builtin_amdgcn_mfma_f32_16x16x32_bf16(wf[p][kt], xf[kt], acc, 0, 0, 0);
            float v0 = acc[0] + bv[p][0]; v0 = v0 > 0.f ? v0 : 0.f;
            float v1 = acc[1] + bv[p][1]; v1 = v1 > 0.f ? v1 : 0.f;
            float v2 = acc[2] + bv[p][2]; v2 = v2 > 0.f ? v2 : 0.f;
            float v3 = acc[3] + bv[p][3]; v3 = v3 > 0.f ? v3 : 0.f;
            u32x2 ov = {(unsigned)f2b(v0) | ((unsigned)f2b(v1) << 16),
                        (unsigned)f2b(v2) | ((unsigned)f2b(v3) << 16)};
            *(u32x2*)(Y + (size_t)row * HID + col0 + p * 16 + lk * 4) = ov;
        }
        if (!more) break;
#pragma unroll
        for (int kt = 0; kt < K / 32; ++kt) xf[kt] = xn[kt];
        T = Tn;
    }
}

// ---- aggr role (aggr3 shape): 32 rows/block, 16 thr/row x 8B, col-half split
// (XCD working set 2x1.28MB), b<->XCD affinity via bid&7.
// DUAL: G = gather(SE,sidx) + gather(IE,iidx); SINGLE: G = gather(SE,sidx).
template<bool DUAL>
__device__ __forceinline__ void aggr_role(
    const unsigned short* __restrict__ SE, const unsigned short* __restrict__ IE,
    const int* __restrict__ sidx, const int* __restrict__ iidx,
    unsigned short* __restrict__ G, int bid) {
    __shared__ int sh[32][33];
    const int t = threadIdx.x;
    const int b = bid & 7;
    const int hc = bid >> 3;
    const int h = hc >= ANCH ? 1 : 0;
    const int c = hc - h * ANCH;
    const int n0 = c * 32;

    if constexpr (DUAL) {
#pragma unroll
        for (int q = 0; q < 2; ++q) {
            const int e = t + q * 512;
            const int r = e >> 5, k = e & 31;
            int nr = n0 + r; if (nr > NNODE - 1) nr = NNODE - 1;
            sh[r][k] = (k < KN) ? sidx[nr * KN + k] : iidx[nr * KN + (k - KN)];
        }
    } else {
        const int r = t >> 4, k = t & 15;
        int nr = n0 + r; if (nr > NNODE - 1) nr = NNODE - 1;
        sh[r][k] = sidx[nr * KN + k];
    }
    __syncthreads();

    const int r = t >> 4, p = t & 15;
    const int col0 = h * 64 + p * 4;
    const int n = n0 + r;
    const size_t base = (size_t)b * NNODE * HID + col0;

    f32x2 a0 = {0.f, 0.f}, a1 = {0.f, 0.f};
    {
        u32x2 vs[16];
#pragma unroll
        for (int j = 0; j < 16; ++j)
            vs[j] = *(const u32x2*)(SE + base + (size_t)sh[r][j] * HID);
#pragma unroll
        for (int j = 0; j < 16; ++j) {
            unsigned u0 = vs[j][0], u1 = vs[j][1];
            a0 += (f32x2){__uint_as_float(u0 << 16), __uint_as_float(u0 & 0xffff0000u)};
            a1 += (f32x2){__uint_as_float(u1 << 16), __uint_as_float(u1 & 0xffff0000u)};
        }
    }
    if constexpr (DUAL) {
        u32x2 vi[16];
#pragma unroll
        for (int j = 0; j < 16; ++j)
            vi[j] = *(const u32x2*)(IE + base + (size_t)sh[r][16 + j] * HID);
#pragma unroll
        for (int j = 0; j < 16; ++j) {
            unsigned u0 = vi[j][0], u1 = vi[j][1];
            a0 += (f32x2){__uint_as_float(u0 << 16), __uint_as_float(u0 & 0xffff0000u)};
            a1 += (f32x2){__uint_as_float(u1 << 16), __uint_as_float(u1 & 0xffff0000u)};
        }
    }

    if (n < NNODE) {
        u32x2 ov = {(unsigned)f2b(a0.x) | ((unsigned)f2b(a0.y) << 16),
                    (unsigned)f2b(a1.x) | ((unsigned)f2b(a1.y) << 16)};
        *(u32x2*)(G + ((size_t)b * NNODE + n) * HID + col0) = ov;
    }
}

// ---- update role: Y = relu([G0|G1|H] @ Wut^T + bu), persistent W, stride loop.
// KK=256: A=[G0|H]; KK=384: A=[G0|G1|H] (Wut has duplicated aggr rows).
template<int KK>
__device__ __forceinline__ void update_role(
    int lb, int stride,
    const unsigned short* __restrict__ G0, const unsigned short* __restrict__ G1,
    const unsigned short* __restrict__ H,
    const unsigned short* __restrict__ Wut, const float* __restrict__ bu,
    float* __restrict__ Yf, unsigned short* __restrict__ Yb, int writeb) {
    const int t = threadIdx.x, w = t >> 6, lane = t & 63;
    const int lrow = lane & 15, lk = lane >> 4;
    const int rs = w & 1, ng = w >> 1;
    const int col0 = ng * 32;
    constexpr int NF = KK / 32;

    short8 wf[2][NF];
    f32x4 bv[2];
#pragma unroll
    for (int p = 0; p < 2; ++p) {
        bv[p] = *(const f32x4*)(bu + col0 + p * 16 + lk * 4);
#pragma unroll
        for (int kt = 0; kt < NF; ++kt)
            wf[p][kt] = *(const short8*)(Wut + (col0 + p * 16 + lrow) * KK + kt * 32 + lk * 8);
    }

    for (int T = lb; T < NTILES; T += stride) {
        const int row = T * 32 + rs * 16 + lrow;
        short8 xf[NF];
#pragma unroll
        for (int kt = 0; kt < 4; ++kt) {
            xf[kt] = *(const short8*)(G0 + (size_t)row * HID + kt * 32 + lk * 8);
            if constexpr (KK == 384) {
                xf[4 + kt] = *(const short8*)(G1 + (size_t)row * HID + kt * 32 + lk * 8);
                xf[8 + kt] = *(const short8*)(H + (size_t)row * HID + kt * 32 + lk * 8);
            } else {
                xf[4 + kt] = *(const short8*)(H + (size_t)row * HID + kt * 32 + lk * 8);
            }
        }
#pragma unroll
        for (int p = 0; p < 2; ++p) {
            f32x4 acc = {0.f, 0.f, 0.f, 0.f};
#pragma unroll
            for (int kt = 0; kt < NF; ++kt)
                acc = __builtin_amdgcn_mfma_f32_16x16x32_bf16(wf[p][kt], xf[kt], acc, 0, 0, 0);
            f32x4 o;
#pragma unroll
            for (int j = 0; j < 4; ++j) {
                float v = acc[j] + bv[p][j];
                o[j] = v > 0.f ? v : 0.f;
            }
            *(f32x4*)(Yf + (size_t)row * HID + col0 + p * 16 + lk * 4) = o;
            if (writeb) {
                u32x2 ov = {(unsigned)f2b(o[0]) | ((unsigned)f2b(o[1]) << 16),
                            (unsigned)f2b(o[2]) | ((unsigned)f2b(o[3]) << 16)};
                *(u32x2*)(Yb + (size_t)row * HID + col0 + p * 16 + lk * 4) = ov;
            }
        }
    }
}

// ---------------- kernels ----------------
__global__ __launch_bounds__(512) void k_embed1(
    const float* __restrict__ state, const float* __restrict__ internal,
    const unsigned short* __restrict__ W1t, const float* __restrict__ b1,
    unsigned short* __restrict__ Y0, unsigned short* __restrict__ Y1) {
    embed_role<64, true>(blockIdx.x, gridDim.x, 2 * NTILES, state, internal, W1t, b1, Y0, Y1);
}

// aggr-dual [0,AGRID) || embed<128> [AGRID, AGRID+1250)
__global__ __launch_bounds__(512) void k_aggrD_embed(
    const unsigned short* __restrict__ SE, const unsigned short* __restrict__ IE,
    const int* __restrict__ sidx, const int* __restrict__ iidx,
    unsigned short* __restrict__ G,
    const unsigned short* __restrict__ X, const unsigned short* __restrict__ W2t,
    const float* __restrict__ b2, unsigned short* __restrict__ Y) {
    if (blockIdx.x < AGRID) aggr_role<true>(SE, IE, sidx, iidx, G, blockIdx.x);
    else embed_role<128, false>(blockIdx.x - AGRID, 1250, NTILES, X, nullptr, W2t, b2, Y, nullptr);
}

// aggr-single [0,AGRID) || embed<128> [AGRID, AGRID+1250)
__global__ __launch_bounds__(512) void k_aggrS_embed(
    const unsigned short* __restrict__ SRC, const int* __restrict__ idx,
    unsigned short* __restrict__ G,
    const unsigned short* __restrict__ X, const unsigned short* __restrict__ W2t,
    const float* __restrict__ b2, unsigned short* __restrict__ Y) {
    if (blockIdx.x < AGRID) aggr_role<false>(SRC, nullptr, idx, nullptr, G, blockIdx.x);
    else embed_role<128, false>(blockIdx.x - AGRID, 1250, NTILES, X, nullptr, W2t, b2, Y, nullptr);
}

__global__ __launch_bounds__(512) void k_aggrS(
    const unsigned short* __restrict__ SRC, const int* __restrict__ idx,
    unsigned short* __restrict__ G) {
    aggr_role<false>(SRC, nullptr, idx, nullptr, G, blockIdx.x);
}

__global__ __launch_bounds__(512) void k_aggrD(
    const unsigned short* __restrict__ SE, const unsigned short* __restrict__ IE,
    const int* __restrict__ sidx, const int* __restrict__ iidx,
    unsigned short* __restrict__ G) {
    aggr_role<true>(SE, IE, sidx, iidx, G, blockIdx.x);
}

__global__ __launch_bounds__(512) void k_embedS(
    const unsigned short* __restrict__ X, const unsigned short* __restrict__ W2t,
    const float* __restrict__ b2, unsigned short* __restrict__ Y) {
    embed_role<128, false>(blockIdx.x, gridDim.x, NTILES, X, nullptr, W2t, b2, Y, nullptr);
}

__global__ __launch_bounds__(512) void k_update256(
    const unsigned short* __restrict__ G, const unsigned short* __restrict__ H,
    const unsigned short* __restrict__ Wut, const float* __restrict__ bu,
    float* __restrict__ Yf, unsigned short* __restrict__ Yb, int writeb) {
    update_role<256>(blockIdx.x, gridDim.x, G, nullptr, H, Wut, bu, Yf, Yb, writeb);
}

__global__ __launch_bounds__(512) void k_update384(
    const unsigned short* __restrict__ Gs, const unsigned short* __restrict__ Gi,
    const unsigned short* __restrict__ H,
    const unsigned short* __restrict__ Wut, const float* __restrict__ bu,
    float* __restrict__ Yf) {
    update_role<384>(blockIdx.x, gridDim.x, Gs, Gi, H, Wut, bu, Yf, nullptr, 0);
}

extern "C" void kernel_launch(void* const* d_in, const int* in_sizes, int n_in,
                              void* d_out, int out_size, void* d_ws, size_t ws_size,
                              hipStream_t stream) {
    const float* state    = (const float*)d_in[0];
    const float* internal = (const float*)d_in[1];
    const int*   sidx     = (const int*)d_in[2];
    const int*   iidx     = (const int*)d_in[3];
    const float* W1  = (const float*)d_in[4];
    const float* b1  = (const float*)d_in[5];
    const float* W2  = (const float*)d_in[6];
    const float* b2  = (const float*)d_in[7];
    const float* Wu1 = (const float*)d_in[8];
    const float* bu1 = (const float*)d_in[9];
    const float* Wu2 = (const float*)d_in[10];
    const float* bu2 = (const float*)d_in[11];

    float* hu1 = (float*)d_out;
    float* hu2 = hu1 + (size_t)ROWS * HID;

    unsigned short* W1t     = (unsigned short*)d_ws;       // 8192
    unsigned short* W2t     = W1t + 8192;                  // 16384
    unsigned short* Wu1t    = W2t + 16384;                 // 32768 (K=256)
    unsigned short* Wu2t384 = Wu1t + 32768;                // 49152 (K=384, dup)
    unsigned short* Wu2t256 = Wu2t384 + 49152;             // 32768 (fallback)
    unsigned short* buf0 = Wu2t256 + 32768;                // weights total 139264
    unsigned short* buf1 = buf0 + (size_t)ROWS * HID;      // 10.24M elems each
    unsigned short* buf2 = buf1 + (size_t)ROWS * HID;
    unsigned short* buf3 = buf2 + (size_t)ROWS * HID;
    unsigned short* buf4 = buf3 + (size_t)ROWS * HID;

    const size_t need_big = ((size_t)139264 + 5 * (size_t)ROWS * HID) * 2;
    const bool big = ws_size >= need_big;

    dim3 b256(256), b512(512);

    wconv_all<<<544, b256, 0, stream>>>(W1, W2, Wu1, Wu2,
                                        W1t, W2t, Wu1t, Wu2t384, Wu2t256);

    // K1: layer-1 embeddings SE1->buf0, IE1->buf1
    k_embed1<<<1250, b512, 0, stream>>>(state, internal, W1t, b1, buf0, buf1);

    if (big) {
        // K2: aggr1 (buf0,buf1 -> buf2)  ||  se2-embed (buf0 -> buf3)
        k_aggrD_embed<<<AGRID + 1250, b512, 0, stream>>>(
            buf0, buf1, sidx, iidx, buf2, buf0, W2t, b2, buf3);
        // K3: hu1 = relu([G|IE1]@Wu1+bu1) -> d_out f32 + bf16 buf0
        k_update256<<<1250, b512, 0, stream>>>(buf2, buf1, Wu1t, bu1, hu1, buf0, 1);
        // K4: aggr2-SE (buf3 -> buf2 via sidx)  ||  ie2-embed (buf0 -> buf1)
        k_aggrS_embed<<<AGRID + 1250, b512, 0, stream>>>(
            buf3, sidx, buf2, buf0, W2t, b2, buf1);
        // K5: aggr2-IE (buf1 -> buf4 via iidx)
        k_aggrS<<<AGRID, b512, 0, stream>>>(buf1, iidx, buf4);
        // K6: hu2 = relu([Gs|Gi|ie2]@Wu2_384+bu2) -> d_out
        k_update384<<<1250, b512, 0, stream>>>(buf2, buf4, buf1, Wu2t384, bu2, hu2);
    } else {
        // 3-buffer sequential fallback; hu2 region doubles as bf16 G scratch.
        unsigned short* Ghu2 = (unsigned short*)hu2;
        // aggr1 -> Ghu2 || se2-embed buf0 -> buf2
        k_aggrD_embed<<<AGRID + 1250, b512, 0, stream>>>(
            buf0, buf1, sidx, iidx, Ghu2, buf0, W2t, b2, buf2);
        // hu1 (reads Ghu2; writes hu1 region only) + bf16 -> buf0
        k_update256<<<1250, b512, 0, stream>>>(Ghu2, buf1, Wu1t, bu1, hu1, buf0, 1);
        // ie2: buf0 -> buf1
        k_embedS<<<1250, b512, 0, stream>>>(buf0, W2t, b2, buf1);
        // aggr2 (SE=buf2 se2, IE=buf1 ie2) -> buf0
        k_aggrD<<<AGRID, b512, 0, stream>>>(buf2, buf1, sidx, iidx, buf0);
        // hu2 = relu([G|ie2]@Wu2+bu2) -> d_out
        k_update256<<<1250, b512, 0, stream>>>(buf0, buf1, Wu2t256, bu2, hu2, nullptr, 0);
    }
}

// Round 11
// 237.932 us; speedup vs baseline: 1.1316x; 1.1316x over previous
//
#include <hip/hip_runtime.h>

#define HID 128
#define NNODE 10000
#define KN 16
#define ROWS 80000    // BATCH * NNODE
#define NTILES 2500   // ROWS / 32
#define ANCH 313      // ceil(NNODE/32) aggr row-chunks
#define AGRID (8 * 2 * ANCH)   // 5008 aggr blocks

typedef __attribute__((ext_vector_type(8))) short short8;   // 8 bf16 (4 VGPRs)
typedef __attribute__((ext_vector_type(4))) float f32x4;
typedef __attribute__((ext_vector_type(2))) float f32x2;
typedef __attribute__((ext_vector_type(2))) unsigned int u32x2;

__device__ __forceinline__ unsigned short f2b(float f) {
    unsigned u = __float_as_uint(f);
    u += 0x7FFFu + ((u >> 16) & 1u);       // round-to-nearest-even
    return (unsigned short)(u >> 16);
}

// Weight transpose+convert: W1t[128][64], W2t[128][128], Wu1t[128][256], Wu2t[128][256].
__global__ __launch_bounds__(256) void wconv_all(
    const float* __restrict__ W1, const float* __restrict__ W2,
    const float* __restrict__ Wu1, const float* __restrict__ Wu2,
    unsigned short* __restrict__ W1t, unsigned short* __restrict__ W2t,
    unsigned short* __restrict__ Wu1t, unsigned short* __restrict__ Wu2t) {
    int idx = blockIdx.x * 256 + threadIdx.x;   // < 90112
    const float* W; unsigned short* Wt; int K; int off;
    if (idx < 8192)       { W = W1;  Wt = W1t;  K = 64;  off = idx; }
    else if (idx < 24576) { W = W2;  Wt = W2t;  K = 128; off = idx - 8192; }
    else if (idx < 57344) { W = Wu1; Wt = Wu1t; K = 256; off = idx - 24576; }
    else                  { W = Wu2; Wt = Wu2t; K = 256; off = idx - 57344; }
    int n = off & 127, k = off >> 7;
    Wt[n * K + k] = f2b(W[off]);
}

// ---- swizzled LDS tile helpers: [32 rows][128 bf16 cols], byte ^= (row&7)<<4
__device__ __forceinline__ void lds_write8(unsigned short* Yt, int row, int bc, u32x2 v) {
    *(u32x2*)((char*)Yt + row * 256 + (bc ^ ((row & 7) << 4))) = v;
}
__device__ __forceinline__ short8 lds_read16(const unsigned short* Yt, int row, int bc) {
    return *(const short8*)((const char*)Yt + row * 256 + (bc ^ ((row & 7) << 4)));
}

// K1: layer-1 embeds + fused se2.
// Tiles 0..2499: SE1 = relu(state@W1+b1) -> global + LDS; se2 = relu(SE1@W2+b2).
// Tiles 2500..4999: IE1 = relu(internal@W1+b1).
__global__ __launch_bounds__(512) void k_embed1_fused(
    const float* __restrict__ state, const float* __restrict__ internal,
    const unsigned short* __restrict__ W1t, const float* __restrict__ b1,
    const unsigned short* __restrict__ W2t, const float* __restrict__ b2,
    unsigned short* __restrict__ SE1, unsigned short* __restrict__ IE1,
    unsigned short* __restrict__ se2) {
    __shared__ __align__(16) unsigned short Yt[32 * 128];   // 8 KB
    const int t = threadIdx.x, w = t >> 6, lane = t & 63;
    const int lrow = lane & 15, lk = lane >> 4;
    const int rs = w & 1, ng = w >> 1;
    const int col0 = ng * 32;
    const int row_l = rs * 16 + lrow;

    short8 wf[2][2];
    f32x4 bv1[2], bv2[2];
#pragma unroll
    for (int p = 0; p < 2; ++p) {
        bv1[p] = *(const f32x4*)(b1 + col0 + p * 16 + lk * 4);
        bv2[p] = *(const f32x4*)(b2 + col0 + p * 16 + lk * 4);
#pragma unroll
        for (int kt = 0; kt < 2; ++kt)
            wf[p][kt] = *(const short8*)(W1t + (col0 + p * 16 + lrow) * 64 + kt * 32 + lk * 8);
    }

    for (int T = blockIdx.x; T < 2 * NTILES; T += 1250) {
        const int half = T >= NTILES;
        const float* X = half ? internal : state;
        unsigned short* Y = half ? IE1 : SE1;
        const int row = (T - half * NTILES) * 32 + row_l;

        short8 xf[2];
#pragma unroll
        for (int kt = 0; kt < 2; ++kt) {
            const float* p4 = X + (size_t)row * 64 + kt * 32 + lk * 8;
            f32x4 f0 = *(const f32x4*)p4;
            f32x4 f1 = *(const f32x4*)(p4 + 4);
            short8 v;
#pragma unroll
            for (int e = 0; e < 4; ++e) { v[e] = (short)f2b(f0[e]); v[4 + e] = (short)f2b(f1[e]); }
            xf[kt] = v;
        }

#pragma unroll
        for (int p = 0; p < 2; ++p) {
            f32x4 acc = {0.f, 0.f, 0.f, 0.f};
            acc = __builtin_amdgcn_mfma_f32_16x16x32_bf16(wf[p][0], xf[0], acc, 0, 0, 0);
            acc = __builtin_amdgcn_mfma_f32_16x16x32_bf16(wf[p][1], xf[1], acc, 0, 0, 0);
            float v0 = acc[0] + bv1[p][0]; v0 = v0 > 0.f ? v0 : 0.f;
            float v1 = acc[1] + bv1[p][1]; v1 = v1 > 0.f ? v1 : 0.f;
            float v2 = acc[2] + bv1[p][2]; v2 = v2 > 0.f ? v2 : 0.f;
            float v3 = acc[3] + bv1[p][3]; v3 = v3 > 0.f ? v3 : 0.f;
            u32x2 ov = {(unsigned)f2b(v0) | ((unsigned)f2b(v1) << 16),
                        (unsigned)f2b(v2) | ((unsigned)f2b(v3) << 16)};
            *(u32x2*)(Y + (size_t)row * HID + col0 + p * 16 + lk * 4) = ov;
            if (!half) lds_write8(Yt, row_l, col0 * 2 + p * 32 + lk * 8, ov);
        }

        if (!half) {   // fused se2 = relu(SE1_tile @ W2 + b2)
            __syncthreads();
            short8 x2[4];
#pragma unroll
            for (int kt = 0; kt < 4; ++kt)
                x2[kt] = lds_read16(Yt, row_l, kt * 64 + lk * 16);
            __syncthreads();
#pragma unroll
            for (int p = 0; p < 2; ++p) {
                f32x4 acc = {0.f, 0.f, 0.f, 0.f};
#pragma unroll
                for (int kt = 0; kt < 4; ++kt) {
                    short8 w2f = *(const short8*)(W2t + (col0 + p * 16 + lrow) * 128 + kt * 32 + lk * 8);
                    acc = __builtin_amdgcn_mfma_f32_16x16x32_bf16(w2f, x2[kt], acc, 0, 0, 0);
                }
                float v0 = acc[0] + bv2[p][0]; v0 = v0 > 0.f ? v0 : 0.f;
                float v1 = acc[1] + bv2[p][1]; v1 = v1 > 0.f ? v1 : 0.f;
                float v2 = acc[2] + bv2[p][2]; v2 = v2 > 0.f ? v2 : 0.f;
                float v3 = acc[3] + bv2[p][3]; v3 = v3 > 0.f ? v3 : 0.f;
                u32x2 ov = {(unsigned)f2b(v0) | ((unsigned)f2b(v1) << 16),
                            (unsigned)f2b(v2) | ((unsigned)f2b(v3) << 16)};
                *(u32x2*)(se2 + (size_t)row * HID + col0 + p * 16 + lk * 4) = ov;
            }
        }
    }
}

// aggr (aggr3 shape): 32 rows/block, 16 thr/row x 8B, col-half split
// (XCD working set 2x1.28MB), b<->XCD affinity via bid&7.
__global__ __launch_bounds__(512) void k_aggrD(
    const unsigned short* __restrict__ SE, const unsigned short* __restrict__ IE,
    const int* __restrict__ sidx, const int* __restrict__ iidx,
    unsigned short* __restrict__ G) {
    __shared__ int sh[32][33];
    const int t = threadIdx.x;
    const int b = blockIdx.x & 7;
    const int hc = blockIdx.x >> 3;
    const int h = hc >= ANCH ? 1 : 0;
    const int c = hc - h * ANCH;
    const int n0 = c * 32;

#pragma unroll
    for (int q = 0; q < 2; ++q) {
        const int e = t + q * 512;
        const int r = e >> 5, k = e & 31;
        int nr = n0 + r; if (nr > NNODE - 1) nr = NNODE - 1;
        sh[r][k] = (k < KN) ? sidx[nr * KN + k] : iidx[nr * KN + (k - KN)];
    }
    __syncthreads();

    const int r = t >> 4, p = t & 15;
    const int col0 = h * 64 + p * 4;
    const int n = n0 + r;
    const size_t base = (size_t)b * NNODE * HID + col0;

    f32x2 a0 = {0.f, 0.f}, a1 = {0.f, 0.f};
    {
        u32x2 vs[16];
#pragma unroll
        for (int j = 0; j < 16; ++j)
            vs[j] = *(const u32x2*)(SE + base + (size_t)sh[r][j] * HID);
#pragma unroll
        for (int j = 0; j < 16; ++j) {
            unsigned u0 = vs[j][0], u1 = vs[j][1];
            a0 += (f32x2){__uint_as_float(u0 << 16), __uint_as_float(u0 & 0xffff0000u)};
            a1 += (f32x2){__uint_as_float(u1 << 16), __uint_as_float(u1 & 0xffff0000u)};
        }
    }
    {
        u32x2 vi[16];
#pragma unroll
        for (int j = 0; j < 16; ++j)
            vi[j] = *(const u32x2*)(IE + base + (size_t)sh[r][16 + j] * HID);
#pragma unroll
        for (int j = 0; j < 16; ++j) {
            unsigned u0 = vi[j][0], u1 = vi[j][1];
            a0 += (f32x2){__uint_as_float(u0 << 16), __uint_as_float(u0 & 0xffff0000u)};
            a1 += (f32x2){__uint_as_float(u1 << 16), __uint_as_float(u1 & 0xffff0000u)};
        }
    }

    if (n < NNODE) {
        u32x2 ov = {(unsigned)f2b(a0.x) | ((unsigned)f2b(a0.y) << 16),
                    (unsigned)f2b(a1.x) | ((unsigned)f2b(a1.y) << 16)};
        *(u32x2*)(G + ((size_t)b * NNODE + n) * HID + col0) = ov;
    }
}

// K3: hu1 = relu([G|H]@Wu1+bu1) -> f32 d_out, tile parked in LDS,
// then fused ie2 = relu(hu1_tile @ W2 + b2) -> bf16.
__global__ __launch_bounds__(512) void k_update1_fused(
    const unsigned short* __restrict__ G, const unsigned short* __restrict__ H,
    const unsigned short* __restrict__ Wu1t, const float* __restrict__ bu1,
    const unsigned short* __restrict__ W2t, const float* __restrict__ b2,
    float* __restrict__ hu1, unsigned short* __restrict__ ie2) {
    __shared__ __align__(16) unsigned short Yt[32 * 128];
    const int t = threadIdx.x, w = t >> 6, lane = t & 63;
    const int lrow = lane & 15, lk = lane >> 4;
    const int rs = w & 1, ng = w >> 1;
    const int col0 = ng * 32;
    const int row_l = rs * 16 + lrow;

    short8 wf[2][8];
    f32x4 bv[2], bv2[2];
#pragma unroll
    for (int p = 0; p < 2; ++p) {
        bv[p]  = *(const f32x4*)(bu1 + col0 + p * 16 + lk * 4);
        bv2[p] = *(const f32x4*)(b2  + col0 + p * 16 + lk * 4);
#pragma unroll
        for (int kt = 0; kt < 8; ++kt)
            wf[p][kt] = *(const short8*)(Wu1t + (col0 + p * 16 + lrow) * 256 + kt * 32 + lk * 8);
    }

    for (int T = blockIdx.x; T < NTILES; T += 1250) {
        const int row = T * 32 + row_l;
        short8 xf[8];
#pragma unroll
        for (int kt = 0; kt < 4; ++kt) {
            xf[kt]     = *(const short8*)(G + (size_t)row * HID + kt * 32 + lk * 8);
            xf[4 + kt] = *(const short8*)(H + (size_t)row * HID + kt * 32 + lk * 8);
        }
#pragma unroll
        for (int p = 0; p < 2; ++p) {
            f32x4 acc = {0.f, 0.f, 0.f, 0.f};
#pragma unroll
            for (int kt = 0; kt < 8; ++kt)
                acc = __builtin_amdgcn_mfma_f32_16x16x32_bf16(wf[p][kt], xf[kt], acc, 0, 0, 0);
            f32x4 o;
#pragma unroll
            for (int j = 0; j < 4; ++j) {
                float v = acc[j] + bv[p][j];
                o[j] = v > 0.f ? v : 0.f;
            }
            *(f32x4*)(hu1 + (size_t)row * HID + col0 + p * 16 + lk * 4) = o;
            u32x2 ov = {(unsigned)f2b(o[0]) | ((unsigned)f2b(o[1]) << 16),
                        (unsigned)f2b(o[2]) | ((unsigned)f2b(o[3]) << 16)};
            lds_write8(Yt, row_l, col0 * 2 + p * 32 + lk * 8, ov);
        }

        __syncthreads();
        short8 x2[4];
#pragma unroll
        for (int kt = 0; kt < 4; ++kt)
            x2[kt] = lds_read16(Yt, row_l, kt * 64 + lk * 16);
        __syncthreads();
#pragma unroll
        for (int p = 0; p < 2; ++p) {
            f32x4 acc = {0.f, 0.f, 0.f, 0.f};
#pragma unroll
            for (int kt = 0; kt < 4; ++kt) {
                short8 w2f = *(const short8*)(W2t + (col0 + p * 16 + lrow) * 128 + kt * 32 + lk * 8);
                acc = __builtin_amdgcn_mfma_f32_16x16x32_bf16(w2f, x2[kt], acc, 0, 0, 0);
            }
            float v0 = acc[0] + bv2[p][0]; v0 = v0 > 0.f ? v0 : 0.f;
            float v1 = acc[1] + bv2[p][1]; v1 = v1 > 0.f ? v1 : 0.f;
            float v2 = acc[2] + bv2[p][2]; v2 = v2 > 0.f ? v2 : 0.f;
            float v3 = acc[3] + bv2[p][3]; v3 = v3 > 0.f ? v3 : 0.f;
            u32x2 ov = {(unsigned)f2b(v0) | ((unsigned)f2b(v1) << 16),
                        (unsigned)f2b(v2) | ((unsigned)f2b(v3) << 16)};
            *(u32x2*)(ie2 + (size_t)row * HID + col0 + p * 16 + lk * 4) = ov;
        }
    }
}

// K5: hu2 = relu([G|H]@Wu2+bu2) -> f32 d_out. Persistent W, grid-stride.
__global__ __launch_bounds__(512) void k_update2(
    const unsigned short* __restrict__ G, const unsigned short* __restrict__ H,
    const unsigned short* __restrict__ Wut, const float* __restrict__ bu,
    float* __restrict__ Yf) {
    const int t = threadIdx.x, w = t >> 6, lane = t & 63;
    const int lrow = lane & 15, lk = lane >> 4;
    const int rs = w & 1, ng = w >> 1;
    const int col0 = ng * 32;

    short8 wf[2][8];
    f32x4 bv[2];
#pragma unroll
    for (int p = 0; p < 2; ++p) {
        bv[p] = *(const f32x4*)(bu + col0 + p * 16 + lk * 4);
#pragma unroll
        for (int kt = 0; kt < 8; ++kt)
            wf[p][kt] = *(const short8*)(Wut + (col0 + p * 16 + lrow) * 256 + kt * 32 + lk * 8);
    }

    for (int T = blockIdx.x; T < NTILES; T += gridDim.x) {
        const int row = T * 32 + rs * 16 + lrow;
        short8 xf[8];
#pragma unroll
        for (int kt = 0; kt < 4; ++kt) {
            xf[kt]     = *(const short8*)(G + (size_t)row * HID + kt * 32 + lk * 8);
            xf[4 + kt] = *(const short8*)(H + (size_t)row * HID + kt * 32 + lk * 8);
        }
#pragma unroll
        for (int p = 0; p < 2; ++p) {
            f32x4 acc = {0.f, 0.f, 0.f, 0.f};
#pragma unroll
            for (int kt = 0; kt < 8; ++kt)
                acc = __builtin_amdgcn_mfma_f32_16x16x32_bf16(wf[p][kt], xf[kt], acc, 0, 0, 0);
            f32x4 o;
#pragma unroll
            for (int j = 0; j < 4; ++j) {
                float v = acc[j] + bv[p][j];
                o[j] = v > 0.f ? v : 0.f;
            }
            *(f32x4*)(Yf + (size_t)row * HID + col0 + p * 16 + lk * 4) = o;
        }
    }
}

extern "C" void kernel_launch(void* const* d_in, const int* in_sizes, int n_in,
                              void* d_out, int out_size, void* d_ws, size_t ws_size,
                              hipStream_t stream) {
    const float* state    = (const float*)d_in[0];
    const float* internal = (const float*)d_in[1];
    const int*   sidx     = (const int*)d_in[2];
    const int*   iidx     = (const int*)d_in[3];
    const float* W1  = (const float*)d_in[4];
    const float* b1  = (const float*)d_in[5];
    const float* W2  = (const float*)d_in[6];
    const float* b2  = (const float*)d_in[7];
    const float* Wu1 = (const float*)d_in[8];
    const float* bu1 = (const float*)d_in[9];
    const float* Wu2 = (const float*)d_in[10];
    const float* bu2 = (const float*)d_in[11];

    float* hu1 = (float*)d_out;
    float* hu2 = hu1 + (size_t)ROWS * HID;

    unsigned short* W1t  = (unsigned short*)d_ws;          // 8192
    unsigned short* W2t  = W1t + 8192;                     // 16384
    unsigned short* Wu1t = W2t + 16384;                    // 32768
    unsigned short* Wu2t = Wu1t + 32768;                   // 32768
    unsigned short* buf0 = Wu2t + 32768;                   // weights total 90112
    unsigned short* buf1 = buf0 + (size_t)ROWS * HID;      // 10.24M elems each
    unsigned short* buf2 = buf1 + (size_t)ROWS * HID;
    unsigned short* buf3 = buf2 + (size_t)ROWS * HID;

    const size_t need_big = ((size_t)90112 + 4 * (size_t)ROWS * HID) * 2;
    const bool big = ws_size >= need_big;

    dim3 b256(256), b512(512);

    wconv_all<<<352, b256, 0, stream>>>(W1, W2, Wu1, Wu2, W1t, W2t, Wu1t, Wu2t);

    // K1: SE1->buf0 (+fused se2->buf2), IE1->buf1
    k_embed1_fused<<<1250, b512, 0, stream>>>(state, internal, W1t, b1, W2t, b2,
                                              buf0, buf1, buf2);

    unsigned short* G1 = big ? buf3 : (unsigned short*)hu2;   // bf16 scratch

    // K2: aggr1 (SE1, IE1) -> G1
    k_aggrD<<<AGRID, b512, 0, stream>>>(buf0, buf1, sidx, iidx, G1);

    // K3: hu1 = relu([G1|IE1]@Wu1+bu1) -> d_out; fused ie2 -> buf0 (SE1 dead)
    k_update1_fused<<<1250, b512, 0, stream>>>(G1, buf1, Wu1t, bu1, W2t, b2, hu1, buf0);

    // K4: aggr2 (se2=buf2, ie2=buf0) -> buf1 (IE1 dead)
    k_aggrD<<<AGRID, b512, 0, stream>>>(buf2, buf0, sidx, iidx, buf1);

    // K5: hu2 = relu([G2|ie2]@Wu2+bu2) -> d_out
    k_update2<<<1250, b512, 0, stream>>>(buf1, buf0, Wu2t, bu2, hu2);
}